// Round 2
// baseline (428.597 us; speedup 1.0000x reference)
//
#include <hip/hip_runtime.h>

// Dynamic per-group (G=128) asymmetric int8 fake-quantize, fp32 in/out.
// Layout: 8192 x 8192 fp32, groups along last dim -> 128 contiguous floats.
// One group = 32 consecutive lanes x float4. Reduction via shfl_xor within
// the 32-lane half-wave (masks 1..16 never cross halves on wave64).

constexpr float QMIN = -128.0f;
constexpr float QMAX = 127.0f;
constexpr float EPSF = 1.1920928955078125e-07f;  // fp32 eps

__global__ __launch_bounds__(256) void dsq_kernel(
    const float* __restrict__ x, float* __restrict__ out, int n4) {
  const float4* __restrict__ x4 = reinterpret_cast<const float4*>(x);
  float4* __restrict__ o4 = reinterpret_cast<float4*>(out);

  int tid = blockIdx.x * blockDim.x + threadIdx.x;
  int stride = gridDim.x * blockDim.x;  // multiple of 32 -> group alignment kept

  for (int i = tid; i < n4; i += stride) {
    float4 v = x4[i];

    // per-thread min/max of 4 elems
    float mn = fminf(fminf(v.x, v.y), fminf(v.z, v.w));
    float mx = fmaxf(fmaxf(v.x, v.y), fmaxf(v.z, v.w));

    // butterfly reduce across the 32 lanes owning this group
    #pragma unroll
    for (int m = 1; m < 32; m <<= 1) {
      mn = fminf(mn, __shfl_xor(mn, m, 64));
      mx = fmaxf(mx, __shfl_xor(mx, m, 64));
    }

    // observer always includes zero (asymmetric affine)
    mn = fminf(mn, 0.0f);
    mx = fmaxf(mx, 0.0f);

    float scale = fmaxf((mx - mn) * (1.0f / 255.0f), EPSF);
    // zero_point = clip(round(QMIN - mn/scale), QMIN, QMAX); round = half-even
    float zp = fminf(fmaxf(rintf(QMIN - mn / scale), QMIN), QMAX);

    float4 o;
    o.x = (fminf(fmaxf(rintf(v.x / scale) + zp, QMIN), QMAX) - zp) * scale;
    o.y = (fminf(fmaxf(rintf(v.y / scale) + zp, QMIN), QMAX) - zp) * scale;
    o.z = (fminf(fmaxf(rintf(v.z / scale) + zp, QMIN), QMAX) - zp) * scale;
    o.w = (fminf(fmaxf(rintf(v.w / scale) + zp, QMIN), QMAX) - zp) * scale;

    o4[i] = o;
  }
}

extern "C" void kernel_launch(void* const* d_in, const int* in_sizes, int n_in,
                              void* d_out, int out_size, void* d_ws, size_t ws_size,
                              hipStream_t stream) {
  const float* x = (const float*)d_in[0];
  float* out = (float*)d_out;
  int n4 = out_size / 4;  // 8192*8192/4 float4s

  // full residency: 2048 blocks x 256 thr = 524288 threads (32 waves/CU x 256 CU)
  int blocks = 2048;
  dsq_kernel<<<blocks, 256, 0, stream>>>(x, out, n4);
}

// Round 3
// 418.119 us; speedup vs baseline: 1.0251x; 1.0251x over previous
//
#include <hip/hip_runtime.h>

// Dynamic per-group (G=128) asymmetric int8 fake-quantize, fp32 in/out.
// 8192x8192 fp32; groups = 128 contiguous floats = 32 float4s.
// Mapping: 16 consecutive lanes own one group; each lane loads float4 #l and
// #(l+16) of the group (both loads fully coalesced 256B segments).
// Min/max reduction: 4-level shfl_xor butterfly within the 16-lane subgroup
// (masks 1,2,4,8 never cross the subgroup on wave64).
// Per-element divide replaced by one IEEE divide per group + multiply
// (max extra error: 1 quant step ~0.027, threshold 0.109).

typedef float f32x4 __attribute__((ext_vector_type(4)));

constexpr float QMIN = -128.0f;
constexpr float QMAX = 127.0f;
constexpr float EPSF = 1.1920928955078125e-07f;  // fp32 eps

__global__ __launch_bounds__(256) void dsq_kernel(
    const float* __restrict__ x, float* __restrict__ out, int n8) {
  const f32x4* __restrict__ x4 = reinterpret_cast<const f32x4*>(x);
  f32x4* __restrict__ o4 = reinterpret_cast<f32x4*>(out);

  int t = blockIdx.x * blockDim.x + threadIdx.x;
  int nthreads = gridDim.x * blockDim.x;  // multiple of 16 -> lane/group map stable

  for (int p = t; p < n8; p += nthreads) {
    // group g = p >> 4 ; lane-in-group l = p & 15
    int i0 = ((p >> 4) << 5) + (p & 15);
    f32x4 v0 = __builtin_nontemporal_load(&x4[i0]);
    f32x4 v1 = __builtin_nontemporal_load(&x4[i0 + 16]);

    float mn = fminf(fminf(fminf(v0.x, v0.y), fminf(v0.z, v0.w)),
                     fminf(fminf(v1.x, v1.y), fminf(v1.z, v1.w)));
    float mx = fmaxf(fmaxf(fmaxf(v0.x, v0.y), fmaxf(v0.z, v0.w)),
                     fmaxf(fmaxf(v1.x, v1.y), fmaxf(v1.z, v1.w)));

    // butterfly across the 16 lanes owning this group
    #pragma unroll
    for (int m = 1; m < 16; m <<= 1) {
      mn = fminf(mn, __shfl_xor(mn, m, 64));
      mx = fmaxf(mx, __shfl_xor(mx, m, 64));
    }

    // observer always includes zero (asymmetric affine)
    mn = fminf(mn, 0.0f);
    mx = fmaxf(mx, 0.0f);

    float scale = fmaxf((mx - mn) * (1.0f / 255.0f), EPSF);
    float inv = 1.0f / scale;  // one IEEE divide per group
    // zero_point with true divide (matches ref at clamp boundaries)
    float zp = fminf(fmaxf(rintf(QMIN - mn / scale), QMIN), QMAX);

    f32x4 o0, o1;
    o0.x = (fminf(fmaxf(rintf(v0.x * inv) + zp, QMIN), QMAX) - zp) * scale;
    o0.y = (fminf(fmaxf(rintf(v0.y * inv) + zp, QMIN), QMAX) - zp) * scale;
    o0.z = (fminf(fmaxf(rintf(v0.z * inv) + zp, QMIN), QMAX) - zp) * scale;
    o0.w = (fminf(fmaxf(rintf(v0.w * inv) + zp, QMIN), QMAX) - zp) * scale;
    o1.x = (fminf(fmaxf(rintf(v1.x * inv) + zp, QMIN), QMAX) - zp) * scale;
    o1.y = (fminf(fmaxf(rintf(v1.y * inv) + zp, QMIN), QMAX) - zp) * scale;
    o1.z = (fminf(fmaxf(rintf(v1.z * inv) + zp, QMIN), QMAX) - zp) * scale;
    o1.w = (fminf(fmaxf(rintf(v1.w * inv) + zp, QMIN), QMAX) - zp) * scale;

    __builtin_nontemporal_store(o0, &o4[i0]);
    __builtin_nontemporal_store(o1, &o4[i0 + 16]);
  }
}

extern "C" void kernel_launch(void* const* d_in, const int* in_sizes, int n_in,
                              void* d_out, int out_size, void* d_ws, size_t ws_size,
                              hipStream_t stream) {
  const float* x = (const float*)d_in[0];
  float* out = (float*)d_out;
  int n8 = out_size / 8;  // float4-pairs: 8 floats per thread-iteration

  // full residency: 2048 blocks x 256 thr = 524288 threads; 16 iters each
  dsq_kernel<<<2048, 256, 0, stream>>>(x, out, n8);
}